// Round 2
// 1213.368 us; speedup vs baseline: 1.0272x; 1.0272x over previous
//
#include <hip/hip_runtime.h>
#include <cstdint>
#include <cstddef>

#define N_VAR  16384
#define N_CHK  8192
#define N_EDGE 65536
#define BATCH  1024

static constexpr float LLR_CLIP = 15.0f;
static constexpr float ABS_MIN_F = 6.1180464e-7f;   // -log(tanh(15/2)) as fp32
static constexpr float EPS1 = 0.999999f;            // 1 - 1e-6

// ---------- helpers ----------
__device__ __forceinline__ float4 ld4(const float* __restrict__ p, int row, int t) {
    return ((const float4*)(p + (size_t)row * BATCH))[t];
}
__device__ __forceinline__ void st4(float* __restrict__ p, int row, int t, float4 v) {
    ((float4*)(p + (size_t)row * BATCH))[t] = v;
}

// log(tanh(|clip(x)|_clamped / 2)) plus neg indicator.
// MUST be bit-identical between loop1 and loop2 of k2_fused (LOO cancellation at the
// atanh cliff), hence a single inline function used by both.
__device__ __forceinline__ float loglam_f(float nv, float& neg) {
    float lam = fminf(fmaxf(nv, -LLR_CLIP), LLR_CLIP);
    neg = (lam < 0.0f) ? 1.0f : 0.0f;
    float a = fminf(fmaxf(fabsf(lam), ABS_MIN_F), LLR_CLIP);
    float t = __expf(-a);                      // tanh(a/2) = (1-t)/(1+t)
    return __logf((1.0f - t) / (1.0f + t));
}

// H-step per element: given nv (v2c_new), check totals (cntT, ampT), old msg m -> c2v_new
__device__ __forceinline__ float hstep(float nv, float cntT, float ampT,
                                       float gm, float g, float m) {
    float ng; float ll = loglam_f(nv, ng);
    float cl = cntT - ng;                      // LOO parity count
    float al = fminf(ampT - ll, 0.0f);         // LOO amplitude, clamp exp arg to <= 0
    float sg = (((int)(cl + 0.5f)) & 1) ? -1.0f : 1.0f;
    float x0 = __expf(al) * EPS1;
    float h  = sg * __logf((1.0f + x0) / (1.0f - x0));  // sgn * 2*atanh(x0)
    return gm * m + g * h;
}

// ---------- CSR build ----------
__global__ __launch_bounds__(256) void hist_k(const int* __restrict__ vi, const int* __restrict__ ci,
                                              int* __restrict__ vcnt, int* __restrict__ ccnt) {
    int e = blockIdx.x * 256 + threadIdx.x;
    if (e < N_EDGE) {
        atomicAdd(&vcnt[vi[e]], 1);
        atomicAdd(&ccnt[ci[e]], 1);
    }
}

// Single-block exclusive scan of PER*1024 ints. cnt becomes the cursor array (= start offsets).
template <int PER>
__global__ __launch_bounds__(1024) void scan_k(int* __restrict__ cnt, int* __restrict__ ptr) {
    __shared__ int sdata[1024];
    const int n = PER * 1024;
    int t = threadIdx.x;
    int base = t * PER;
    int loc[PER];
    int sum = 0;
#pragma unroll
    for (int i = 0; i < PER; i++) { loc[i] = sum; sum += cnt[base + i]; }
    sdata[t] = sum;
    __syncthreads();
    for (int off = 1; off < 1024; off <<= 1) {
        int v = (t >= off) ? sdata[t - off] : 0;
        __syncthreads();
        sdata[t] += v;
        __syncthreads();
    }
    int excl = (t == 0) ? 0 : sdata[t - 1];
#pragma unroll
    for (int i = 0; i < PER; i++) {
        int p = excl + loc[i];
        ptr[base + i] = p;
        cnt[base + i] = p;   // cursor for scatter
    }
    if (t == 1023) ptr[n] = sdata[1023];
}

// cedg2[q] = (edge, var) packed: kills the dependent cedg[i] -> vi[e] load chain in k2.
__global__ __launch_bounds__(256) void scatter_k(const int* __restrict__ vi, const int* __restrict__ ci,
                                                 int* __restrict__ vcur, int* __restrict__ ccur,
                                                 int* __restrict__ vedg, int2* __restrict__ cedg2) {
    int e = blockIdx.x * 256 + threadIdx.x;
    if (e < N_EDGE) {
        int v = vi[e];
        int p = atomicAdd(&vcur[v], 1);    vedg[p] = e;
        int q = atomicAdd(&ccur[ci[e]], 1); cedg2[q] = make_int2(e, v);
    }
}

// ---------- K1/K3: per-variable  out[v] = Wi*chn[v] + We * sum_e msg[e] ----------
// Used twice: (msg = c2v)     -> acc_v   (V-step accumulator)
//             (msg = out_c2v) -> out_marg (M-step marginals)
__global__ __launch_bounds__(256) void k_var_acc(const float* __restrict__ chn,
                                                 const float* __restrict__ msg,
                                                 const float* __restrict__ Wi_p,
                                                 const float* __restrict__ We_p,
                                                 const int* __restrict__ vptr,
                                                 const int* __restrict__ vedg,
                                                 float* __restrict__ out) {
    int v = blockIdx.x, t = threadIdx.x;
    float Wi = Wi_p[0], We = We_p[0];
    float4 a = ld4(chn, v, t);
    a.x *= Wi; a.y *= Wi; a.z *= Wi; a.w *= Wi;
    int s = vptr[v], e1 = vptr[v + 1];
#pragma unroll 2
    for (int i = s; i < e1; i++) {
        int e = vedg[i];
        float4 m = ld4(msg, e, t);
        a.x += We * m.x; a.y += We * m.y; a.z += We * m.z; a.w += We * m.w;
    }
    st4(out, v, t, a);
}

// ---------- K2 fused: per-check, two passes over the check's edges ----------
// Loop 1: v2c_new (V-step + damping) -> out_v2c, accumulate check totals (cnt, amp) in regs.
// Loop 2: H-step LOO + damping -> out_c2v, re-reading out_v2c/c2v (L2-hot: this block just
//         touched those exact rows; same thread wrote the exact element it re-reads).
// This removes the acc_cnt/acc_amp round-trip (67 MB write + ~536 MB gathered reads) and
// k3's cold 268 MB re-read of out_v2c from the old 3-pass structure.
__global__ __launch_bounds__(256) void k2_fused(const float* __restrict__ c2v,
                                                const float* __restrict__ v2c,
                                                const float* __restrict__ acc_v,
                                                const float* __restrict__ We_p,
                                                const float* __restrict__ g_p,
                                                const int* __restrict__ cptr,
                                                const int2* __restrict__ cedg2,
                                                float* __restrict__ out_v2c,
                                                float* __restrict__ out_c2v) {
    int c = blockIdx.x, t = threadIdx.x;
    float We = We_p[0], g = g_p[0], gm = 1.0f - g;
    float4 cnt = make_float4(0.f, 0.f, 0.f, 0.f);
    float4 amp = make_float4(0.f, 0.f, 0.f, 0.f);
    int s = cptr[c], e1 = cptr[c + 1];
#pragma unroll 2
    for (int i = s; i < e1; i++) {
        int2 ev = cedg2[i];
        float4 m  = ld4(c2v, ev.x, t);
        float4 p  = ld4(v2c, ev.x, t);
        float4 av = ld4(acc_v, ev.y, t);
        float4 nv;
        nv.x = gm * p.x + g * (av.x - We * m.x);
        nv.y = gm * p.y + g * (av.y - We * m.y);
        nv.z = gm * p.z + g * (av.z - We * m.z);
        nv.w = gm * p.w + g * (av.w - We * m.w);
        st4(out_v2c, ev.x, t, nv);
        float ng, ll;
        ll = loglam_f(nv.x, ng); cnt.x += ng; amp.x += ll;
        ll = loglam_f(nv.y, ng); cnt.y += ng; amp.y += ll;
        ll = loglam_f(nv.z, ng); cnt.z += ng; amp.z += ll;
        ll = loglam_f(nv.w, ng); cnt.w += ng; amp.w += ll;
    }
#pragma unroll 2
    for (int i = s; i < e1; i++) {
        int e = cedg2[i].x;
        float4 nv = ld4(out_v2c, e, t);      // fp32 round-trip is exact -> loglam bits identical
        float4 m  = ld4(c2v, e, t);          // L1/L2 hit (read in loop 1)
        float4 cn;
        cn.x = hstep(nv.x, cnt.x, amp.x, gm, g, m.x);
        cn.y = hstep(nv.y, cnt.y, amp.y, gm, g, m.y);
        cn.z = hstep(nv.z, cnt.z, amp.z, gm, g, m.z);
        cn.w = hstep(nv.w, cnt.w, amp.w, gm, g, m.w);
        st4(out_c2v, e, t, cn);
    }
}

extern "C" void kernel_launch(void* const* d_in, const int* in_sizes, int n_in,
                              void* d_out, int out_size, void* d_ws, size_t ws_size,
                              hipStream_t stream) {
    const float* chn   = (const float*)d_in[0];
    const float* c2v   = (const float*)d_in[1];
    const float* v2c   = (const float*)d_in[2];
    const float* Wi_p  = (const float*)d_in[3];
    const float* We_p  = (const float*)d_in[4];
    const float* g_p   = (const float*)d_in[5];
    const int*   vi    = (const int*)d_in[6];
    const int*   ci    = (const int*)d_in[7];

    float* out_c2v  = (float*)d_out;
    float* out_v2c  = out_c2v + (size_t)N_EDGE * BATCH;
    float* out_marg = out_v2c + (size_t)N_EDGE * BATCH;
    float* acc_v    = out_marg;   // scratch: K1 writes, K2 reads, K3 overwrites with final output

    // workspace: ints only now (totals live in registers inside k2_fused)
    int*  iws   = (int*)d_ws;
    int*  vcnt  = iws;                  // N_VAR      (count -> cursor)
    int*  ccnt  = vcnt + N_VAR;         // N_CHK      (count -> cursor)
    int*  vptr  = ccnt + N_CHK;         // N_VAR+1
    int*  cptr  = vptr + (N_VAR + 1);   // N_CHK+1
    int*  vedg  = cptr + (N_CHK + 1);   // N_EDGE
    int2* cedg2 = (int2*)(vedg + N_EDGE);  // N_EDGE int2 (offset is 8B-aligned: 114690*4 % 8 == 0)

    // ---- CSR build (cheap; same work every call) ----
    hipMemsetAsync(vcnt, 0, (size_t)(N_VAR + N_CHK) * sizeof(int), stream);
    hist_k<<<N_EDGE / 256, 256, 0, stream>>>(vi, ci, vcnt, ccnt);
    scan_k<N_VAR / 1024><<<1, 1024, 0, stream>>>(vcnt, vptr);
    scan_k<N_CHK / 1024><<<1, 1024, 0, stream>>>(ccnt, cptr);
    scatter_k<<<N_EDGE / 256, 256, 0, stream>>>(vi, ci, vcnt, ccnt, vedg, cedg2);

    // ---- main passes ----
    k_var_acc<<<N_VAR, 256, 0, stream>>>(chn, c2v, Wi_p, We_p, vptr, vedg, acc_v);
    k2_fused<<<N_CHK, 256, 0, stream>>>(c2v, v2c, acc_v, We_p, g_p, cptr, cedg2,
                                        out_v2c, out_c2v);
    k_var_acc<<<N_VAR, 256, 0, stream>>>(chn, out_c2v, Wi_p, We_p, vptr, vedg, out_marg);
}